// Round 1
// 330.168 us; speedup vs baseline: 1.0247x; 1.0247x over previous
//
#include <hip/hip_runtime.h>
#include <hip/hip_bf16.h>
#include <math.h>

#define N_ATOMS  50000
#define N_MOTIFS 50000
#define N_SEG    (N_MOTIFS + N_ATOMS)   // 100000 combined segments
#define N_INC    600000
#define N_GRAPHS 512
#define H        64
#define MOTIF_DIM 94
#define HOUT     128
#define BN_EPS   1e-5f
#define NZ       101
#define SCAN_NBLK 98                    // ceil(100000/1024)
#define TL       32                     // motif rows per block (f+c fused)
#define NBLK_L   ((N_MOTIFS + TL - 1) / TL)  // 1563
#define EZCAP    640                    // LDS edge-list cap (mean 384; global fallback)
#define NREP     32                     // BN accumulator replicas

__device__ __forceinline__ float softplus_fast(float x) {
    return fmaxf(x, 0.0f) + __logf(1.0f + __expf(-fabsf(x)));
}
__device__ __forceinline__ float gate_f(float f, float c) {
    float sig = __builtin_amdgcn_rcpf(1.0f + __expf(-f));
    return sig * softplus_fast(c);
}

// degree histogram (R13 form — R14's 4-edge variant showed a pathological replay)
__global__ __launch_bounds__(256) void count_kernel(const int* __restrict__ he,
                                                    unsigned* __restrict__ cnt) {
    int e = blockIdx.x * 256 + threadIdx.x;
    if (e >= N_INC) return;
    atomicAdd(&cnt[he[N_INC + e]], 1u);
    atomicAdd(&cnt[N_MOTIFS + he[e]], 1u);
}

// phase 1: per-block (1024 elems) sums
__global__ __launch_bounds__(256) void scan_part(const unsigned* __restrict__ cnt,
                                                 unsigned* __restrict__ part) {
    __shared__ unsigned red[256];
    int b = blockIdx.x, t = threadIdx.x;
    int i0 = b * 1024 + t * 4;
    unsigned s = 0;
#pragma unroll
    for (int i = 0; i < 4; i++) { int idx = i0 + i; if (idx < N_SEG) s += cnt[idx]; }
    red[t] = s;
    __syncthreads();
    for (int off = 128; off > 0; off >>= 1) {
        if (t < off) red[t] += red[t + off];
        __syncthreads();
    }
    if (t == 0) part[b] = red[0];
}

// aux: block 0 = exclusive scan of block sums; blocks 1..NZ = projected z-tables
// (interleaved (col*2+sel)); block NZ+1 = interleaved big-W (rows 2H..2H+93) + bias.
__global__ __launch_bounds__(256) void aux_kernel(const unsigned* __restrict__ part,
                                                  unsigned* __restrict__ part_pre,
                                                  const float* __restrict__ table,
                                                  const float* __restrict__ w_f,
                                                  const float* __restrict__ w_c,
                                                  const float* __restrict__ b_f,
                                                  const float* __restrict__ b_c,
                                                  float* __restrict__ atab_fc,
                                                  float* __restrict__ ptab_fc,
                                                  float* __restrict__ w_fc,
                                                  float* __restrict__ b_fc) {
    int t = threadIdx.x;
    if (blockIdx.x == 0) {
        __shared__ unsigned s[128];
        if (t < 128) s[t] = (t < SCAN_NBLK) ? part[t] : 0u;
        __syncthreads();
        for (int off = 1; off < 128; off <<= 1) {
            unsigned add = (t < 128 && t >= off) ? s[t - off] : 0u;
            __syncthreads();
            if (t < 128) s[t] += add;
            __syncthreads();
        }
        if (t < SCAN_NBLK) part_pre[t] = (t > 0) ? s[t - 1] : 0u;
        return;
    }
    int z = blockIdx.x - 1;
    if (z >= NZ) {   // build w_fc[94][128] (col*2+sel interleave) + b_fc[128]
        if (t < 128) {
            int sel = t & 1, col = t >> 1;
            b_fc[t] = (sel ? b_c : b_f)[col];
            const float* ws = sel ? w_c : w_f;
            for (int k = 0; k < MOTIF_DIM; k++)
                w_fc[(size_t)k * 128 + t] = ws[(size_t)(2 * H + k) * H + col];
        }
        return;
    }
    __shared__ float trow[H];
    if (t < H) trow[t] = table[(size_t)z * H + t];
    __syncthreads();
    if (t < 128) {
        int sel = (t >= 64) ? 1 : 0;
        int jj = t & 63;
        const float* ws = sel ? w_c : w_f;
        float aacc = 0.0f, pacc = 0.0f;
        for (int k = 0; k < H; k++) {
            float tv = trow[k];
            aacc += tv * ws[(size_t)k * H + jj];
            pacc += tv * ws[(size_t)(H + k) * H + jj];
        }
        atab_fc[(size_t)z * 128 + jj * 2 + sel] = aacc;
        ptab_fc[(size_t)z * 128 + jj * 2 + sel] = pacc;
    }
}

// phase 3: block-local exclusive scan + global offset -> base, cur (+sentinel)
__global__ __launch_bounds__(256) void scan_down(const unsigned* __restrict__ cnt,
                                                 const unsigned* __restrict__ part_pre,
                                                 unsigned* __restrict__ base,
                                                 unsigned* __restrict__ cur) {
    __shared__ unsigned s[256];
    int b = blockIdx.x, t = threadIdx.x;
    int i0 = b * 1024 + t * 4;
    unsigned c[4];
#pragma unroll
    for (int i = 0; i < 4; i++) { int idx = i0 + i; c[i] = (idx < N_SEG) ? cnt[idx] : 0u; }
    s[t] = c[0] + c[1] + c[2] + c[3];
    __syncthreads();
    for (int off = 1; off < 256; off <<= 1) {
        unsigned add = (t >= off) ? s[t - off] : 0u;
        __syncthreads();
        s[t] += add;
        __syncthreads();
    }
    unsigned pre = part_pre[b] + ((t > 0) ? s[t - 1] : 0u);
#pragma unroll
    for (int i = 0; i < 4; i++) {
        int idx = i0 + i;
        if (idx < N_SEG) { base[idx] = pre; cur[idx] = pre; pre += c[i]; }
    }
    if (b == SCAN_NBLK - 1 && t == 255) base[N_SEG] = pre;  // sentinel = 2*N_INC
}

// XCD-partitioned CSR fill (R13 form)
__global__ __launch_bounds__(256) void fill_kernel(const int* __restrict__ he,
                                                   const int* __restrict__ atom_z,
                                                   unsigned* __restrict__ cur,
                                                   int* __restrict__ csr_val) {
    int cls = blockIdx.x & 7;
    int bi  = blockIdx.x >> 3;
    int nb  = gridDim.x >> 3;
    for (int e = bi * 256 + threadIdx.x; e < N_INC; e += nb * 256) {
        int s = he[e];
        int h = he[N_INC + e];
        if (((h >> 4) & 7) == cls) {
            unsigned p = atomicAdd(&cur[h], 1u);
            csr_val[p] = atom_z[s];
        }
        if (((s >> 4) & 7) == cls) {
            unsigned q = atomicAdd(&cur[N_MOTIFS + s], 1u);
            csr_val[q] = h;
        }
    }
}

// Motif kernel, f AND c fused per block via (col*2+sel)-interleaved tables.
// Each thread: 4 rows x (2 cols x 2 sel) accumulators = same 4x4 float shape
// as the proven split kernel; writes m_fc directly (interleave kernel deleted).
__global__ __launch_bounds__(256) void motif_fused(const unsigned* __restrict__ base,
                                                   const int* __restrict__ csr_val,
                                                   const float* __restrict__ ptab_fc,
                                                   const float* __restrict__ motif_attr,
                                                   const float* __restrict__ w_fc,
                                                   const float* __restrict__ b_fc,
                                                   float* __restrict__ m_fc) {
    __shared__ float z[TL][100];
    __shared__ int   ez[EZCAP];
    __shared__ int   rowlo[TL + 1];
    __shared__ float invd[TL];
    int m0 = blockIdx.x * TL;
    int tid = threadIdx.x;
    unsigned blockBase = base[m0];
    if (tid <= TL) {
        int gm = m0 + tid;
        rowlo[tid] = (int)(base[(gm < N_MOTIFS) ? gm : N_MOTIFS] - blockBase);
    }
    __syncthreads();
    if (tid < TL) {
        int d = rowlo[tid + 1] - rowlo[tid];
        invd[tid] = 1.0f / fmaxf((float)d, 1.0f);
    }
    int nE = rowlo[TL];
    int nStage = (nE < EZCAP) ? nE : EZCAP;
    for (int k = tid; k < nStage; k += 256) ez[k] = csr_val[blockBase + k];
    for (int idx = tid; idx < TL * 47; idx += 256) {
        int m = idx / 47, k2 = idx % 47;
        int gm = m0 + m;
        float2 v = make_float2(0.f, 0.f);
        if (gm < N_MOTIFS) v = ((const float2*)motif_attr)[(size_t)gm * 47 + k2];
        *(float2*)&z[m][k2 * 2] = v;
    }
    __syncthreads();

    int rg = tid >> 5;        // 8 row groups x 4 rows = 32 rows
    int cg = tid & 31;        // 32 col-pair groups
    int q  = cg * 4;          // float offset in 128-wide interleaved row

    float4 bias4 = *(const float4*)(b_fc + q);   // (f0,c0,f1,c1)
    float acc[4][4];
#pragma unroll
    for (int i = 0; i < 4; i++) {
        int r = rg * 4 + i;
        int lo = rowlo[r], d = rowlo[r + 1] - lo;
        float g0 = 0.f, g1 = 0.f, g2 = 0.f, g3 = 0.f;
        int k = 0;
        for (; k + 8 <= d; k += 8) {
            int zz[8];
#pragma unroll
            for (int u = 0; u < 8; u++) {
                int o = lo + k + u;
                zz[u] = (o < EZCAP) ? ez[o] : csr_val[blockBase + o];
            }
            float4 p[8];
#pragma unroll
            for (int u = 0; u < 8; u++) p[u] = *(const float4*)(ptab_fc + (size_t)zz[u] * 128 + q);
#pragma unroll
            for (int u = 0; u < 8; u++) {
                g0 += p[u].x; g1 += p[u].y; g2 += p[u].z; g3 += p[u].w;
            }
        }
        for (; k < d; k++) {
            int o0 = lo + k;
            int z0 = (o0 < EZCAP) ? ez[o0] : csr_val[blockBase + o0];
            float4 p0 = *(const float4*)(ptab_fc + (size_t)z0 * 128 + q);
            g0 += p0.x; g1 += p0.y; g2 += p0.z; g3 += p0.w;
        }
        float iv = invd[r];
        acc[i][0] = bias4.x + g0 * iv;
        acc[i][1] = bias4.y + g1 * iv;
        acc[i][2] = bias4.z + g2 * iv;
        acc[i][3] = bias4.w + g3 * iv;
    }

    const float* wsrc = w_fc + q;
    float4 wb0 = *(const float4*)(wsrc);
    float4 wb1 = *(const float4*)(wsrc + 128);
    float4 wb2 = *(const float4*)(wsrc + 2 * 128);
    float4 wb3 = *(const float4*)(wsrc + 3 * 128);
#pragma unroll 1
    for (int k = 0; k < 88; k += 4) {
        float4 nw0 = *(const float4*)(wsrc + (size_t)(k + 4) * 128);
        float4 nw1 = *(const float4*)(wsrc + (size_t)(k + 5) * 128);
        float4 nw2 = *(const float4*)(wsrc + (size_t)(k + 6) * 128);
        float4 nw3 = *(const float4*)(wsrc + (size_t)(k + 7) * 128);
        float4 zv[4];
#pragma unroll
        for (int i = 0; i < 4; i++) zv[i] = *(const float4*)&z[rg * 4 + i][k];
#pragma unroll
        for (int i = 0; i < 4; i++) {
            acc[i][0] += zv[i].x * wb0.x + zv[i].y * wb1.x + zv[i].z * wb2.x + zv[i].w * wb3.x;
            acc[i][1] += zv[i].x * wb0.y + zv[i].y * wb1.y + zv[i].z * wb2.y + zv[i].w * wb3.y;
            acc[i][2] += zv[i].x * wb0.z + zv[i].y * wb1.z + zv[i].z * wb2.z + zv[i].w * wb3.z;
            acc[i][3] += zv[i].x * wb0.w + zv[i].y * wb1.w + zv[i].z * wb2.w + zv[i].w * wb3.w;
        }
        wb0 = nw0; wb1 = nw1; wb2 = nw2; wb3 = nw3;
    }
    {   // tail k = 88..91 from wb
        float4 zv[4];
#pragma unroll
        for (int i = 0; i < 4; i++) zv[i] = *(const float4*)&z[rg * 4 + i][88];
#pragma unroll
        for (int i = 0; i < 4; i++) {
            acc[i][0] += zv[i].x * wb0.x + zv[i].y * wb1.x + zv[i].z * wb2.x + zv[i].w * wb3.x;
            acc[i][1] += zv[i].x * wb0.y + zv[i].y * wb1.y + zv[i].z * wb2.y + zv[i].w * wb3.y;
            acc[i][2] += zv[i].x * wb0.z + zv[i].y * wb1.z + zv[i].z * wb2.z + zv[i].w * wb3.z;
            acc[i][3] += zv[i].x * wb0.w + zv[i].y * wb1.w + zv[i].z * wb2.w + zv[i].w * wb3.w;
        }
    }
    {   // tail k = 92,93
        float4 w0 = *(const float4*)(wsrc + (size_t)92 * 128);
        float4 w1 = *(const float4*)(wsrc + (size_t)93 * 128);
        float2 zv[4];
#pragma unroll
        for (int i = 0; i < 4; i++) zv[i] = *(const float2*)&z[rg * 4 + i][92];
#pragma unroll
        for (int i = 0; i < 4; i++) {
            acc[i][0] += zv[i].x * w0.x + zv[i].y * w1.x;
            acc[i][1] += zv[i].x * w0.y + zv[i].y * w1.y;
            acc[i][2] += zv[i].x * w0.z + zv[i].y * w1.z;
            acc[i][3] += zv[i].x * w0.w + zv[i].y * w1.w;
        }
    }
#pragma unroll
    for (int i = 0; i < 4; i++) {
        int gm = m0 + rg * 4 + i;
        if (gm < N_MOTIFS)
            *(float4*)&m_fc[(size_t)gm * 128 + q] =
                make_float4(acc[i][0], acc[i][1], acc[i][2], acc[i][3]);
    }
}

// one wave per atom (contiguous mapping); 8-deep edge batching; ONE float2 load per
// edge from interleaved m_fc; fused BN stats into NREP replicas.
__global__ __launch_bounds__(256) void msg_gather(const unsigned* __restrict__ base,
                                                  const int* __restrict__ csr_val,
                                                  const int* __restrict__ atom_z,
                                                  const float2* __restrict__ atab_fc,
                                                  const float2* __restrict__ m_fc,
                                                  float* __restrict__ out_mean,
                                                  float* __restrict__ bn_part) {
    int i = blockIdx.x * 4 + (threadIdx.x >> 6);
    int j = threadIdx.x & 63;
    int zi = atom_z[i];                          // wave-uniform -> scalar load
    float2 a = atab_fc[(size_t)zi * H + j];
    unsigned b = base[N_MOTIFS + i];
    unsigned d = base[N_MOTIFS + i + 1] - b;     // sentinel covers last atom
    float acc = 0.0f;
    unsigned k = 0;
    for (; k + 8 <= d; k += 8) {
        int hh[8];
#pragma unroll
        for (int u = 0; u < 8; u++) hh[u] = csr_val[b + k + u];
        float2 v[8];
#pragma unroll
        for (int u = 0; u < 8; u++) v[u] = m_fc[(size_t)hh[u] * H + j];
#pragma unroll
        for (int u = 0; u < 8; u++) acc += gate_f(a.x + v[u].x, a.y + v[u].y);
    }
    for (; k + 2 <= d; k += 2) {
        int h0 = csr_val[b + k], h1 = csr_val[b + k + 1];
        float2 v0 = m_fc[(size_t)h0 * H + j];
        float2 v1 = m_fc[(size_t)h1 * H + j];
        acc += gate_f(a.x + v0.x, a.y + v0.y) + gate_f(a.x + v1.x, a.y + v1.y);
    }
    for (; k < d; k++) {
        int h0 = csr_val[b + k];
        float2 v0 = m_fc[(size_t)h0 * H + j];
        acc += gate_f(a.x + v0.x, a.y + v0.y);
    }
    float v = acc / fmaxf((float)d, 1.0f);
    out_mean[(size_t)i * H + j] = v;
    __shared__ float ssum[256];
    __shared__ float ssq[256];
    ssum[threadIdx.x] = v; ssq[threadIdx.x] = v * v;
    __syncthreads();
    if (threadIdx.x < 64) {
        float* rep = bn_part + (size_t)(blockIdx.x & (NREP - 1)) * 128;
        atomicAdd(&rep[j],      ssum[j] + ssum[64 + j] + ssum[128 + j] + ssum[192 + j]);
        atomicAdd(&rep[64 + j], ssq[j]  + ssq[64 + j]  + ssq[128 + j]  + ssq[192 + j]);
    }
}

// one block per graph: reduce BN replicas + bounds search + BN-apply + residual +
// relu + mean-pool, then the MLP head inline.
__global__ __launch_bounds__(256) void pool_head(const float* __restrict__ out_mean,
                                                 const float* __restrict__ bn_part,
                                                 const float* __restrict__ gamma,
                                                 const float* __restrict__ beta,
                                                 const int* __restrict__ atom_z,
                                                 const float* __restrict__ table,
                                                 const int* __restrict__ batch,
                                                 const float* __restrict__ w_l1,
                                                 const float* __restrict__ b_l1,
                                                 const float* __restrict__ w_out,
                                                 const float* __restrict__ b_out,
                                                 float* __restrict__ out) {
    int g = blockIdx.x;
    int tid = threadIdx.x;
    __shared__ int bounds[2];
    __shared__ float red[256];
    __shared__ float gv[H];
    __shared__ float red2[HOUT];
    __shared__ float bnred[128];
    if (tid < 2) {
        int target = g + tid;
        int lo = 0, hi = N_ATOMS;
        while (lo < hi) {
            int mid = (lo + hi) >> 1;
            if (batch[mid] < target) lo = mid + 1; else hi = mid;
        }
        bounds[tid] = lo;
    }
    if (tid < 128) {
        float s = 0.0f;
        for (int r = 0; r < NREP; r++) s += bn_part[(size_t)r * 128 + tid];
        bnred[tid] = s;
    }
    __syncthreads();
    int s = bounds[0], e = bounds[1];
    int j = tid & 63, w = tid >> 6;
    const float invN = 1.0f / (float)N_ATOMS;
    float mu = bnred[j] * invN;
    float var = bnred[64 + j] * invN - mu * mu;
    float rstd = 1.0f / sqrtf(var + BN_EPS);
    float gm = gamma[j], bt = beta[j];
    float acc = 0.0f;
    for (int i = s + w; i < e; i += 4) {
        float d = out_mean[(size_t)i * H + j];
        float xv = table[(size_t)atom_z[i] * H + j];
        float o = (d - mu) * rstd * gm + bt;
        acc += fmaxf(o + xv, 0.0f);
    }
    red[tid] = acc;
    __syncthreads();
    if (tid < 64)
        gv[j] = (red[j] + red[64 + j] + red[128 + j] + red[192 + j])
                / fmaxf((float)(e - s), 1.0f);
    __syncthreads();
    if (tid < HOUT) {
        float a2 = b_l1[tid];
        for (int k = 0; k < H; k++) a2 += gv[k] * w_l1[(size_t)k * HOUT + tid];
        red2[tid] = softplus_fast(a2) * w_out[tid];
    }
    __syncthreads();
    for (int st = 64; st > 0; st >>= 1) {
        if (tid < st) red2[tid] += red2[tid + st];
        __syncthreads();
    }
    if (tid == 0) out[g] = red2[0] + b_out[0];
}

extern "C" void kernel_launch(void* const* d_in, const int* in_sizes, int n_in,
                              void* d_out, int out_size, void* d_ws, size_t ws_size,
                              hipStream_t stream) {
    const int*   atom_z     = (const int*)  d_in[0];
    const float* motif_attr = (const float*)d_in[1];
    const int*   he         = (const int*)  d_in[2];
    const int*   batch      = (const int*)  d_in[3];
    const float* table      = (const float*)d_in[4];
    const float* w_f        = (const float*)d_in[5];
    const float* b_f        = (const float*)d_in[6];
    const float* w_c        = (const float*)d_in[7];
    const float* b_c        = (const float*)d_in[8];
    const float* gamma      = (const float*)d_in[9];
    const float* beta       = (const float*)d_in[10];
    const float* w_l1       = (const float*)d_in[11];
    const float* b_l1       = (const float*)d_in[12];
    const float* w_out      = (const float*)d_in[13];
    const float* b_out      = (const float*)d_in[14];
    float* out = (float*)d_out;

    // ---- workspace layout (all offsets stay 16B-aligned) ----
    unsigned* cnt     = (unsigned*)d_ws;                   // 100,000 (zeroed)
    float*    bn_part = (float*)(cnt + N_SEG);             // 32*128 (zeroed)
    char*     zero_end = (char*)(bn_part + NREP * 128);
    unsigned* base     = (unsigned*)zero_end;              // 100,001 (+sentinel +pad)
    unsigned* cur      = base + N_SEG + 4;                 // 100,000
    unsigned* part     = cur + N_SEG;                      // 128
    unsigned* part_pre = part + 128;                       // 128
    int*      csr_val  = (int*)(part_pre + 128);           // 1,200,000
    float*    atab_fc  = (float*)(csr_val + 2 * N_INC);    // 101*128
    float*    ptab_fc  = atab_fc + (size_t)NZ * 128;       // 101*128 interleaved
    float*    w_fc     = ptab_fc + (size_t)NZ * 128;       // 94*128 interleaved
    float*    b_fc     = w_fc + (size_t)MOTIF_DIM * 128;   // 128
    float*    m_fc     = b_fc + 128;                       // 50,000*128 interleaved
    float*    out_mean = m_fc + (size_t)N_MOTIFS * 128;    // 3.2M

    size_t zero_bytes = (size_t)(zero_end - (char*)d_ws);
    hipMemsetAsync(d_ws, 0, zero_bytes, stream);

    count_kernel<<<(N_INC + 255) / 256, 256, 0, stream>>>(he, cnt);
    scan_part<<<SCAN_NBLK, 256, 0, stream>>>(cnt, part);
    aux_kernel<<<2 + NZ, 256, 0, stream>>>(part, part_pre, table, w_f, w_c, b_f, b_c,
                                           atab_fc, ptab_fc, w_fc, b_fc);
    scan_down<<<SCAN_NBLK, 256, 0, stream>>>(cnt, part_pre, base, cur);
    fill_kernel<<<1024, 256, 0, stream>>>(he, atom_z, cur, csr_val);
    motif_fused<<<NBLK_L, 256, 0, stream>>>(base, csr_val, ptab_fc, motif_attr,
                                            w_fc, b_fc, m_fc);
    msg_gather<<<N_ATOMS / 4, 256, 0, stream>>>(base, csr_val, atom_z,
                                                (const float2*)atab_fc,
                                                (const float2*)m_fc,
                                                out_mean, bn_part);
    pool_head<<<N_GRAPHS, 256, 0, stream>>>(out_mean, bn_part, gamma, beta,
                                            atom_z, table, batch,
                                            w_l1, b_l1, w_out, b_out, out);
}

// Round 2
// 328.897 us; speedup vs baseline: 1.0287x; 1.0039x over previous
//
#include <hip/hip_runtime.h>
#include <hip/hip_bf16.h>
#include <math.h>

#define N_ATOMS  50000
#define N_MOTIFS 50000
#define N_SEG    (N_MOTIFS + N_ATOMS)   // 100000 combined segments
#define N_INC    600000
#define N_GRAPHS 512
#define H        64
#define MOTIF_DIM 94
#define HOUT     128
#define BN_EPS   1e-5f
#define NZ       101
#define SCAN_NBLK 98                    // ceil(100000/1024)
#define TL       64                     // motif rows per block (f+c fused, R=8)
#define NBLK_L   ((N_MOTIFS + TL - 1) / TL)  // 782
#define EZCAP    1280                   // LDS edge-list cap (mean 768; global fallback)
#define NREP     32                     // BN accumulator replicas

__device__ __forceinline__ float softplus_fast(float x) {
    return fmaxf(x, 0.0f) + __logf(1.0f + __expf(-fabsf(x)));
}
__device__ __forceinline__ float gate_f(float f, float c) {
    float sig = __builtin_amdgcn_rcpf(1.0f + __expf(-f));
    return sig * softplus_fast(c);
}

// degree histogram (R13 form — R14's 4-edge variant showed a pathological replay)
__global__ __launch_bounds__(256) void count_kernel(const int* __restrict__ he,
                                                    unsigned* __restrict__ cnt) {
    int e = blockIdx.x * 256 + threadIdx.x;
    if (e >= N_INC) return;
    atomicAdd(&cnt[he[N_INC + e]], 1u);
    atomicAdd(&cnt[N_MOTIFS + he[e]], 1u);
}

// phase 1: per-block (1024 elems) sums
__global__ __launch_bounds__(256) void scan_part(const unsigned* __restrict__ cnt,
                                                 unsigned* __restrict__ part) {
    __shared__ unsigned red[256];
    int b = blockIdx.x, t = threadIdx.x;
    int i0 = b * 1024 + t * 4;
    unsigned s = 0;
#pragma unroll
    for (int i = 0; i < 4; i++) { int idx = i0 + i; if (idx < N_SEG) s += cnt[idx]; }
    red[t] = s;
    __syncthreads();
    for (int off = 128; off > 0; off >>= 1) {
        if (t < off) red[t] += red[t + off];
        __syncthreads();
    }
    if (t == 0) part[b] = red[0];
}

// aux: block 0 = exclusive scan of block sums; blocks 1..NZ = projected z-tables
// (interleaved (col*2+sel)); block NZ+1 = interleaved big-W (rows 2H..2H+93) + bias.
__global__ __launch_bounds__(256) void aux_kernel(const unsigned* __restrict__ part,
                                                  unsigned* __restrict__ part_pre,
                                                  const float* __restrict__ table,
                                                  const float* __restrict__ w_f,
                                                  const float* __restrict__ w_c,
                                                  const float* __restrict__ b_f,
                                                  const float* __restrict__ b_c,
                                                  float* __restrict__ atab_fc,
                                                  float* __restrict__ ptab_fc,
                                                  float* __restrict__ w_fc,
                                                  float* __restrict__ b_fc) {
    int t = threadIdx.x;
    if (blockIdx.x == 0) {
        __shared__ unsigned s[128];
        if (t < 128) s[t] = (t < SCAN_NBLK) ? part[t] : 0u;
        __syncthreads();
        for (int off = 1; off < 128; off <<= 1) {
            unsigned add = (t < 128 && t >= off) ? s[t - off] : 0u;
            __syncthreads();
            if (t < 128) s[t] += add;
            __syncthreads();
        }
        if (t < SCAN_NBLK) part_pre[t] = (t > 0) ? s[t - 1] : 0u;
        return;
    }
    int z = blockIdx.x - 1;
    if (z >= NZ) {   // build w_fc[94][128] (col*2+sel interleave) + b_fc[128]
        if (t < 128) {
            int sel = t & 1, col = t >> 1;
            b_fc[t] = (sel ? b_c : b_f)[col];
            const float* ws = sel ? w_c : w_f;
            for (int k = 0; k < MOTIF_DIM; k++)
                w_fc[(size_t)k * 128 + t] = ws[(size_t)(2 * H + k) * H + col];
        }
        return;
    }
    __shared__ float trow[H];
    if (t < H) trow[t] = table[(size_t)z * H + t];
    __syncthreads();
    if (t < 128) {
        int sel = (t >= 64) ? 1 : 0;
        int jj = t & 63;
        const float* ws = sel ? w_c : w_f;
        float aacc = 0.0f, pacc = 0.0f;
        for (int k = 0; k < H; k++) {
            float tv = trow[k];
            aacc += tv * ws[(size_t)k * H + jj];
            pacc += tv * ws[(size_t)(H + k) * H + jj];
        }
        atab_fc[(size_t)z * 128 + jj * 2 + sel] = aacc;
        ptab_fc[(size_t)z * 128 + jj * 2 + sel] = pacc;
    }
}

// phase 3: block-local exclusive scan + global offset -> base, cur (+sentinel)
__global__ __launch_bounds__(256) void scan_down(const unsigned* __restrict__ cnt,
                                                 const unsigned* __restrict__ part_pre,
                                                 unsigned* __restrict__ base,
                                                 unsigned* __restrict__ cur) {
    __shared__ unsigned s[256];
    int b = blockIdx.x, t = threadIdx.x;
    int i0 = b * 1024 + t * 4;
    unsigned c[4];
#pragma unroll
    for (int i = 0; i < 4; i++) { int idx = i0 + i; c[i] = (idx < N_SEG) ? cnt[idx] : 0u; }
    s[t] = c[0] + c[1] + c[2] + c[3];
    __syncthreads();
    for (int off = 1; off < 256; off <<= 1) {
        unsigned add = (t >= off) ? s[t - off] : 0u;
        __syncthreads();
        s[t] += add;
        __syncthreads();
    }
    unsigned pre = part_pre[b] + ((t > 0) ? s[t - 1] : 0u);
#pragma unroll
    for (int i = 0; i < 4; i++) {
        int idx = i0 + i;
        if (idx < N_SEG) { base[idx] = pre; cur[idx] = pre; pre += c[i]; }
    }
    if (b == SCAN_NBLK - 1 && t == 255) base[N_SEG] = pre;  // sentinel = 2*N_INC
}

// XCD-partitioned CSR fill (R13 form)
__global__ __launch_bounds__(256) void fill_kernel(const int* __restrict__ he,
                                                   const int* __restrict__ atom_z,
                                                   unsigned* __restrict__ cur,
                                                   int* __restrict__ csr_val) {
    int cls = blockIdx.x & 7;
    int bi  = blockIdx.x >> 3;
    int nb  = gridDim.x >> 3;
    for (int e = bi * 256 + threadIdx.x; e < N_INC; e += nb * 256) {
        int s = he[e];
        int h = he[N_INC + e];
        if (((h >> 4) & 7) == cls) {
            unsigned p = atomicAdd(&cur[h], 1u);
            csr_val[p] = atom_z[s];
        }
        if (((s >> 4) & 7) == cls) {
            unsigned q = atomicAdd(&cur[N_MOTIFS + s], 1u);
            csr_val[q] = h;
        }
    }
}

// Motif kernel, f AND c fused via (col*2+sel)-interleaved tables; TL=64, R=8
// rows per thread (8 rowgroups x 32 col-pair groups). Each thread's 94 float4
// w-loads now feed 8 output rows -> total w L1 traffic halves vs R=4.
__global__ __launch_bounds__(256) void motif_fused(const unsigned* __restrict__ base,
                                                   const int* __restrict__ csr_val,
                                                   const float* __restrict__ ptab_fc,
                                                   const float* __restrict__ motif_attr,
                                                   const float* __restrict__ w_fc,
                                                   const float* __restrict__ b_fc,
                                                   float* __restrict__ m_fc) {
    __shared__ float z[TL][100];
    __shared__ int   ez[EZCAP];
    __shared__ int   rowlo[TL + 1];
    __shared__ float invd[TL];
    int m0 = blockIdx.x * TL;
    int tid = threadIdx.x;
    unsigned blockBase = base[m0];
    if (tid <= TL) {
        int gm = m0 + tid;
        rowlo[tid] = (int)(base[(gm < N_MOTIFS) ? gm : N_MOTIFS] - blockBase);
    }
    __syncthreads();
    if (tid < TL) {
        int d = rowlo[tid + 1] - rowlo[tid];
        invd[tid] = 1.0f / fmaxf((float)d, 1.0f);
    }
    int nE = rowlo[TL];
    int nStage = (nE < EZCAP) ? nE : EZCAP;
    for (int k = tid; k < nStage; k += 256) ez[k] = csr_val[blockBase + k];
    for (int idx = tid; idx < TL * 47; idx += 256) {
        int m = idx / 47, k2 = idx % 47;
        int gm = m0 + m;
        float2 v = make_float2(0.f, 0.f);
        if (gm < N_MOTIFS) v = ((const float2*)motif_attr)[(size_t)gm * 47 + k2];
        *(float2*)&z[m][k2 * 2] = v;
    }
    __syncthreads();

    int rg = tid >> 5;        // 8 row groups x 8 rows = 64 rows
    int cg = tid & 31;        // 32 col-pair groups
    int q  = cg * 4;          // float offset in 128-wide interleaved row

    float4 bias4 = *(const float4*)(b_fc + q);   // (f0,c0,f1,c1)
    float acc[8][4];
#pragma unroll
    for (int i = 0; i < 8; i++) {
        int r = rg * 8 + i;
        int lo = rowlo[r], d = rowlo[r + 1] - lo;
        float g0 = 0.f, g1 = 0.f, g2 = 0.f, g3 = 0.f;
        int k = 0;
        for (; k + 8 <= d; k += 8) {
            int zz[8];
#pragma unroll
            for (int u = 0; u < 8; u++) {
                int o = lo + k + u;
                zz[u] = (o < EZCAP) ? ez[o] : csr_val[blockBase + o];
            }
            float4 p[8];
#pragma unroll
            for (int u = 0; u < 8; u++) p[u] = *(const float4*)(ptab_fc + (size_t)zz[u] * 128 + q);
#pragma unroll
            for (int u = 0; u < 8; u++) {
                g0 += p[u].x; g1 += p[u].y; g2 += p[u].z; g3 += p[u].w;
            }
        }
        for (; k < d; k++) {
            int o0 = lo + k;
            int z0 = (o0 < EZCAP) ? ez[o0] : csr_val[blockBase + o0];
            float4 p0 = *(const float4*)(ptab_fc + (size_t)z0 * 128 + q);
            g0 += p0.x; g1 += p0.y; g2 += p0.z; g3 += p0.w;
        }
        float iv = invd[r];
        acc[i][0] = bias4.x + g0 * iv;
        acc[i][1] = bias4.y + g1 * iv;
        acc[i][2] = bias4.z + g2 * iv;
        acc[i][3] = bias4.w + g3 * iv;
    }

    const float* wsrc = w_fc + q;
    float4 wb0 = *(const float4*)(wsrc);
    float4 wb1 = *(const float4*)(wsrc + 128);
    float4 wb2 = *(const float4*)(wsrc + 2 * 128);
    float4 wb3 = *(const float4*)(wsrc + 3 * 128);
#pragma unroll 1
    for (int k = 0; k < 88; k += 4) {
        float4 nw0 = *(const float4*)(wsrc + (size_t)(k + 4) * 128);
        float4 nw1 = *(const float4*)(wsrc + (size_t)(k + 5) * 128);
        float4 nw2 = *(const float4*)(wsrc + (size_t)(k + 6) * 128);
        float4 nw3 = *(const float4*)(wsrc + (size_t)(k + 7) * 128);
#pragma unroll
        for (int i = 0; i < 8; i++) {
            float4 zv = *(const float4*)&z[rg * 8 + i][k];
            acc[i][0] += zv.x * wb0.x + zv.y * wb1.x + zv.z * wb2.x + zv.w * wb3.x;
            acc[i][1] += zv.x * wb0.y + zv.y * wb1.y + zv.z * wb2.y + zv.w * wb3.y;
            acc[i][2] += zv.x * wb0.z + zv.y * wb1.z + zv.z * wb2.z + zv.w * wb3.z;
            acc[i][3] += zv.x * wb0.w + zv.y * wb1.w + zv.z * wb2.w + zv.w * wb3.w;
        }
        wb0 = nw0; wb1 = nw1; wb2 = nw2; wb3 = nw3;
    }
    {   // tail k = 88..91 from wb
#pragma unroll
        for (int i = 0; i < 8; i++) {
            float4 zv = *(const float4*)&z[rg * 8 + i][88];
            acc[i][0] += zv.x * wb0.x + zv.y * wb1.x + zv.z * wb2.x + zv.w * wb3.x;
            acc[i][1] += zv.x * wb0.y + zv.y * wb1.y + zv.z * wb2.y + zv.w * wb3.y;
            acc[i][2] += zv.x * wb0.z + zv.y * wb1.z + zv.z * wb2.z + zv.w * wb3.z;
            acc[i][3] += zv.x * wb0.w + zv.y * wb1.w + zv.z * wb2.w + zv.w * wb3.w;
        }
    }
    {   // tail k = 92,93
        float4 w0 = *(const float4*)(wsrc + (size_t)92 * 128);
        float4 w1 = *(const float4*)(wsrc + (size_t)93 * 128);
#pragma unroll
        for (int i = 0; i < 8; i++) {
            float2 zv = *(const float2*)&z[rg * 8 + i][92];
            acc[i][0] += zv.x * w0.x + zv.y * w1.x;
            acc[i][1] += zv.x * w0.y + zv.y * w1.y;
            acc[i][2] += zv.x * w0.z + zv.y * w1.z;
            acc[i][3] += zv.x * w0.w + zv.y * w1.w;
        }
    }
#pragma unroll
    for (int i = 0; i < 8; i++) {
        int gm = m0 + rg * 8 + i;
        if (gm < N_MOTIFS)
            *(float4*)&m_fc[(size_t)gm * 128 + q] =
                make_float4(acc[i][0], acc[i][1], acc[i][2], acc[i][3]);
    }
}

// one wave per atom (contiguous mapping); 8-deep edge batching; ONE float2 load per
// edge from interleaved m_fc; fused BN stats into NREP replicas.
__global__ __launch_bounds__(256) void msg_gather(const unsigned* __restrict__ base,
                                                  const int* __restrict__ csr_val,
                                                  const int* __restrict__ atom_z,
                                                  const float2* __restrict__ atab_fc,
                                                  const float2* __restrict__ m_fc,
                                                  float* __restrict__ out_mean,
                                                  float* __restrict__ bn_part) {
    int i = blockIdx.x * 4 + (threadIdx.x >> 6);
    int j = threadIdx.x & 63;
    int zi = atom_z[i];                          // wave-uniform -> scalar load
    float2 a = atab_fc[(size_t)zi * H + j];
    unsigned b = base[N_MOTIFS + i];
    unsigned d = base[N_MOTIFS + i + 1] - b;     // sentinel covers last atom
    float acc = 0.0f;
    unsigned k = 0;
    for (; k + 8 <= d; k += 8) {
        int hh[8];
#pragma unroll
        for (int u = 0; u < 8; u++) hh[u] = csr_val[b + k + u];
        float2 v[8];
#pragma unroll
        for (int u = 0; u < 8; u++) v[u] = m_fc[(size_t)hh[u] * H + j];
#pragma unroll
        for (int u = 0; u < 8; u++) acc += gate_f(a.x + v[u].x, a.y + v[u].y);
    }
    for (; k + 2 <= d; k += 2) {
        int h0 = csr_val[b + k], h1 = csr_val[b + k + 1];
        float2 v0 = m_fc[(size_t)h0 * H + j];
        float2 v1 = m_fc[(size_t)h1 * H + j];
        acc += gate_f(a.x + v0.x, a.y + v0.y) + gate_f(a.x + v1.x, a.y + v1.y);
    }
    for (; k < d; k++) {
        int h0 = csr_val[b + k];
        float2 v0 = m_fc[(size_t)h0 * H + j];
        acc += gate_f(a.x + v0.x, a.y + v0.y);
    }
    float v = acc / fmaxf((float)d, 1.0f);
    out_mean[(size_t)i * H + j] = v;
    __shared__ float ssum[256];
    __shared__ float ssq[256];
    ssum[threadIdx.x] = v; ssq[threadIdx.x] = v * v;
    __syncthreads();
    if (threadIdx.x < 64) {
        float* rep = bn_part + (size_t)(blockIdx.x & (NREP - 1)) * 128;
        atomicAdd(&rep[j],      ssum[j] + ssum[64 + j] + ssum[128 + j] + ssum[192 + j]);
        atomicAdd(&rep[64 + j], ssq[j]  + ssq[64 + j]  + ssq[128 + j]  + ssq[192 + j]);
    }
}

// one block per graph: reduce BN replicas + bounds search + BN-apply + residual +
// relu + mean-pool, then the MLP head inline.
__global__ __launch_bounds__(256) void pool_head(const float* __restrict__ out_mean,
                                                 const float* __restrict__ bn_part,
                                                 const float* __restrict__ gamma,
                                                 const float* __restrict__ beta,
                                                 const int* __restrict__ atom_z,
                                                 const float* __restrict__ table,
                                                 const int* __restrict__ batch,
                                                 const float* __restrict__ w_l1,
                                                 const float* __restrict__ b_l1,
                                                 const float* __restrict__ w_out,
                                                 const float* __restrict__ b_out,
                                                 float* __restrict__ out) {
    int g = blockIdx.x;
    int tid = threadIdx.x;
    __shared__ int bounds[2];
    __shared__ float red[256];
    __shared__ float gv[H];
    __shared__ float red2[HOUT];
    __shared__ float bnred[128];
    if (tid < 2) {
        int target = g + tid;
        int lo = 0, hi = N_ATOMS;
        while (lo < hi) {
            int mid = (lo + hi) >> 1;
            if (batch[mid] < target) lo = mid + 1; else hi = mid;
        }
        bounds[tid] = lo;
    }
    if (tid < 128) {
        float s = 0.0f;
        for (int r = 0; r < NREP; r++) s += bn_part[(size_t)r * 128 + tid];
        bnred[tid] = s;
    }
    __syncthreads();
    int s = bounds[0], e = bounds[1];
    int j = tid & 63, w = tid >> 6;
    const float invN = 1.0f / (float)N_ATOMS;
    float mu = bnred[j] * invN;
    float var = bnred[64 + j] * invN - mu * mu;
    float rstd = 1.0f / sqrtf(var + BN_EPS);
    float gm = gamma[j], bt = beta[j];
    float acc = 0.0f;
    for (int i = s + w; i < e; i += 4) {
        float d = out_mean[(size_t)i * H + j];
        float xv = table[(size_t)atom_z[i] * H + j];
        float o = (d - mu) * rstd * gm + bt;
        acc += fmaxf(o + xv, 0.0f);
    }
    red[tid] = acc;
    __syncthreads();
    if (tid < 64)
        gv[j] = (red[j] + red[64 + j] + red[128 + j] + red[192 + j])
                / fmaxf((float)(e - s), 1.0f);
    __syncthreads();
    if (tid < HOUT) {
        float a2 = b_l1[tid];
        for (int k = 0; k < H; k++) a2 += gv[k] * w_l1[(size_t)k * HOUT + tid];
        red2[tid] = softplus_fast(a2) * w_out[tid];
    }
    __syncthreads();
    for (int st = 64; st > 0; st >>= 1) {
        if (tid < st) red2[tid] += red2[tid + st];
        __syncthreads();
    }
    if (tid == 0) out[g] = red2[0] + b_out[0];
}

extern "C" void kernel_launch(void* const* d_in, const int* in_sizes, int n_in,
                              void* d_out, int out_size, void* d_ws, size_t ws_size,
                              hipStream_t stream) {
    const int*   atom_z     = (const int*)  d_in[0];
    const float* motif_attr = (const float*)d_in[1];
    const int*   he         = (const int*)  d_in[2];
    const int*   batch      = (const int*)  d_in[3];
    const float* table      = (const float*)d_in[4];
    const float* w_f        = (const float*)d_in[5];
    const float* b_f        = (const float*)d_in[6];
    const float* w_c        = (const float*)d_in[7];
    const float* b_c        = (const float*)d_in[8];
    const float* gamma      = (const float*)d_in[9];
    const float* beta       = (const float*)d_in[10];
    const float* w_l1       = (const float*)d_in[11];
    const float* b_l1       = (const float*)d_in[12];
    const float* w_out      = (const float*)d_in[13];
    const float* b_out      = (const float*)d_in[14];
    float* out = (float*)d_out;

    // ---- workspace layout (all offsets stay 16B-aligned) ----
    unsigned* cnt     = (unsigned*)d_ws;                   // 100,000 (zeroed)
    float*    bn_part = (float*)(cnt + N_SEG);             // 32*128 (zeroed)
    char*     zero_end = (char*)(bn_part + NREP * 128);
    unsigned* base     = (unsigned*)zero_end;              // 100,001 (+sentinel +pad)
    unsigned* cur      = base + N_SEG + 4;                 // 100,000
    unsigned* part     = cur + N_SEG;                      // 128
    unsigned* part_pre = part + 128;                       // 128
    int*      csr_val  = (int*)(part_pre + 128);           // 1,200,000
    float*    atab_fc  = (float*)(csr_val + 2 * N_INC);    // 101*128
    float*    ptab_fc  = atab_fc + (size_t)NZ * 128;       // 101*128 interleaved
    float*    w_fc     = ptab_fc + (size_t)NZ * 128;       // 94*128 interleaved
    float*    b_fc     = w_fc + (size_t)MOTIF_DIM * 128;   // 128
    float*    m_fc     = b_fc + 128;                       // 50,000*128 interleaved
    float*    out_mean = m_fc + (size_t)N_MOTIFS * 128;    // 3.2M

    size_t zero_bytes = (size_t)(zero_end - (char*)d_ws);
    hipMemsetAsync(d_ws, 0, zero_bytes, stream);

    count_kernel<<<(N_INC + 255) / 256, 256, 0, stream>>>(he, cnt);
    scan_part<<<SCAN_NBLK, 256, 0, stream>>>(cnt, part);
    aux_kernel<<<2 + NZ, 256, 0, stream>>>(part, part_pre, table, w_f, w_c, b_f, b_c,
                                           atab_fc, ptab_fc, w_fc, b_fc);
    scan_down<<<SCAN_NBLK, 256, 0, stream>>>(cnt, part_pre, base, cur);
    fill_kernel<<<1024, 256, 0, stream>>>(he, atom_z, cur, csr_val);
    motif_fused<<<NBLK_L, 256, 0, stream>>>(base, csr_val, ptab_fc, motif_attr,
                                            w_fc, b_fc, m_fc);
    msg_gather<<<N_ATOMS / 4, 256, 0, stream>>>(base, csr_val, atom_z,
                                                (const float2*)atab_fc,
                                                (const float2*)m_fc,
                                                out_mean, bn_part);
    pool_head<<<N_GRAPHS, 256, 0, stream>>>(out_mean, bn_part, gamma, beta,
                                            atom_z, table, batch,
                                            w_l1, b_l1, w_out, b_out, out);
}